// Round 1
// baseline (1336.993 us; speedup 1.0000x reference)
//
#include <hip/hip_runtime.h>

#define N_NODES 100000
#define N_EDGES 640000
#define D 128

// ---------------------------------------------------------------------------
// k_zero: zero the aggregation buffer (d_out, N*D floats) and deg (N ints)
// ---------------------------------------------------------------------------
__global__ __launch_bounds__(256) void k_zero(float* __restrict__ out,
                                              int* __restrict__ deg) {
    int idx = blockIdx.x * blockDim.x + threadIdx.x;
    const int total4 = (N_NODES * D) / 4;  // 3,200,000 float4
    if (idx < total4) {
        ((float4*)out)[idx] = make_float4(0.f, 0.f, 0.f, 0.f);
    }
    if (idx < N_NODES) deg[idx] = 0;
}

// ---------------------------------------------------------------------------
// k_deg: deg[src[e]] += 1
// ---------------------------------------------------------------------------
__global__ __launch_bounds__(256) void k_deg(const int* __restrict__ src,
                                             int* __restrict__ deg) {
    int e = blockIdx.x * blockDim.x + threadIdx.x;
    if (e < N_EDGES) atomicAdd(&deg[src[e]], 1);
}

// ---------------------------------------------------------------------------
// k_dis_w: dis[n] = deg>0 ? deg^-0.5 : 0 ; also transpose both weights so the
// GEMM can read W^T[k][j] coalesced in j.
// ---------------------------------------------------------------------------
__global__ __launch_bounds__(256) void k_dis_w(const int* __restrict__ deg,
                                               float* __restrict__ dis,
                                               const float* __restrict__ Wm,
                                               const float* __restrict__ Ws,
                                               float* __restrict__ WmT,
                                               float* __restrict__ WsT) {
    int i = blockIdx.x * blockDim.x + threadIdx.x;
    if (i < N_NODES) {
        int d = deg[i];
        dis[i] = (d > 0) ? (1.0f / sqrtf((float)d)) : 0.0f;
    }
    if (i < D * D) {
        int j = i >> 7;    // source row (output col)
        int k = i & 127;   // source col (k index)
        WmT[k * D + j] = Wm[i];
        WsT[k * D + j] = Ws[i];
    }
}

// ---------------------------------------------------------------------------
// k_scatter: agg[dst[e]] += feats[src[e]] * dis[src[e]]
// 32 threads per edge, float4 gather, 4 scalar float atomics per thread.
// ---------------------------------------------------------------------------
__global__ __launch_bounds__(256) void k_scatter(const float* __restrict__ feats,
                                                 const int* __restrict__ src,
                                                 const int* __restrict__ dst,
                                                 const float* __restrict__ dis,
                                                 float* __restrict__ agg) {
    long long t = (long long)blockIdx.x * blockDim.x + threadIdx.x;
    int e  = (int)(t >> 5);
    int c4 = (int)(t & 31);
    if (e >= N_EDGES) return;
    int s = src[e];
    int d = dst[e];
    float sc = dis[s];
    float4 v = ((const float4*)(feats + (size_t)s * D))[c4];
    float* p = agg + (size_t)d * D + c4 * 4;
    atomicAdd(p + 0, v.x * sc);
    atomicAdd(p + 1, v.y * sc);
    atomicAdd(p + 2, v.z * sc);
    atomicAdd(p + 3, v.w * sc);
}

// ---------------------------------------------------------------------------
// k_out: out[n] = (agg[n]*dis[n]) @ Wmsg^T + bmsg + feats[n] @ Wskip^T + bskip
// Block: 32 rows x 128 cols, 256 threads (64,4). Each thread: 2 cols x 8 rows.
// agg rows are staged to LDS before being overwritten (row-local, safe).
// ---------------------------------------------------------------------------
#define TR 32
__global__ __launch_bounds__(256) void k_out(const float* __restrict__ feats,
                                             const float* __restrict__ dis,
                                             const float* __restrict__ WmT,
                                             const float* __restrict__ WsT,
                                             const float* __restrict__ bskip,
                                             const float* __restrict__ bmsg,
                                             float* __restrict__ out) {
    __shared__ float As[TR][D];
    __shared__ float Fs[TR][D];
    int tx = threadIdx.x;            // 0..63
    int ty = threadIdx.y;            // 0..3
    int tid = ty * 64 + tx;
    int row0 = blockIdx.x * TR;

    // stage agg*dis and feats rows into LDS (float4, coalesced)
    for (int i = tid; i < TR * (D / 4); i += 256) {
        int r  = i >> 5;             // 32 float4 per row
        int c4 = i & 31;
        int n = row0 + r;
        float4 a = make_float4(0.f, 0.f, 0.f, 0.f);
        float4 f = a;
        if (n < N_NODES) {
            float sc = dis[n];
            a = ((const float4*)(out + (size_t)n * D))[c4];
            a.x *= sc; a.y *= sc; a.z *= sc; a.w *= sc;
            f = ((const float4*)(feats + (size_t)n * D))[c4];
        }
        ((float4*)&As[r][0])[c4] = a;
        ((float4*)&Fs[r][0])[c4] = f;
    }
    __syncthreads();

    float acc0[8], acc1[8];
#pragma unroll
    for (int r = 0; r < 8; r++) { acc0[r] = 0.f; acc1[r] = 0.f; }

    for (int k = 0; k < D; k += 4) {
        float wm0[4], wm1[4], ws0[4], ws1[4];
#pragma unroll
        for (int q = 0; q < 4; q++) {
            wm0[q] = WmT[(k + q) * D + tx];
            wm1[q] = WmT[(k + q) * D + tx + 64];
            ws0[q] = WsT[(k + q) * D + tx];
            ws1[q] = WsT[(k + q) * D + tx + 64];
        }
#pragma unroll
        for (int r = 0; r < 8; r++) {
            int rr = ty + 4 * r;
            float4 a = *(const float4*)&As[rr][k];
            float4 f = *(const float4*)&Fs[rr][k];
            acc0[r] += a.x * wm0[0] + a.y * wm0[1] + a.z * wm0[2] + a.w * wm0[3]
                     + f.x * ws0[0] + f.y * ws0[1] + f.z * ws0[2] + f.w * ws0[3];
            acc1[r] += a.x * wm1[0] + a.y * wm1[1] + a.z * wm1[2] + a.w * wm1[3]
                     + f.x * ws1[0] + f.y * ws1[1] + f.z * ws1[2] + f.w * ws1[3];
        }
    }

    float b0 = bmsg[tx]      + bskip[tx];
    float b1 = bmsg[tx + 64] + bskip[tx + 64];
#pragma unroll
    for (int r = 0; r < 8; r++) {
        int n = row0 + ty + 4 * r;
        if (n < N_NODES) {
            out[(size_t)n * D + tx]      = acc0[r] + b0;
            out[(size_t)n * D + tx + 64] = acc1[r] + b1;
        }
    }
}

// ---------------------------------------------------------------------------
extern "C" void kernel_launch(void* const* d_in, const int* in_sizes, int n_in,
                              void* d_out, int out_size, void* d_ws, size_t ws_size,
                              hipStream_t stream) {
    const float* feats = (const float*)d_in[0];
    const int*   src   = (const int*)d_in[1];
    const int*   dst   = (const int*)d_in[2];
    const float* Wskip = (const float*)d_in[3];
    const float* bskip = (const float*)d_in[4];
    const float* Wmsg  = (const float*)d_in[5];
    const float* bmsg  = (const float*)d_in[6];
    float* out = (float*)d_out;

    // workspace layout (all 128B-aligned):
    //   [0,        400000)  int   deg[N]
    //   [400000,   800000)  float dis[N]
    //   [800000,   865536)  float WmT[128*128]
    //   [865536,   931072)  float WsT[128*128]
    char* w = (char*)d_ws;
    int*   deg = (int*)w;
    float* dis = (float*)(w + 400000);
    float* WmT = (float*)(w + 800000);
    float* WsT = (float*)(w + 865536);

    // 1. zero agg (d_out) + deg
    hipLaunchKernelGGL(k_zero, dim3(12500), dim3(256), 0, stream, out, deg);
    // 2. degree
    hipLaunchKernelGGL(k_deg, dim3((N_EDGES + 255) / 256), dim3(256), 0, stream,
                       src, deg);
    // 3. deg^-0.5 + weight transposes
    hipLaunchKernelGGL(k_dis_w, dim3((N_NODES + 255) / 256), dim3(256), 0, stream,
                       deg, dis, Wmsg, Wskip, WmT, WsT);
    // 4. scatter-add messages into d_out
    hipLaunchKernelGGL(k_scatter, dim3((N_EDGES * 32) / 256), dim3(256), 0, stream,
                       feats, src, dst, dis, out);
    // 5. fused dual-GEMM epilogue, in-place on d_out
    hipLaunchKernelGGL(k_out, dim3(N_NODES / TR), dim3(64, 4), 0, stream,
                       feats, dis, WmT, WsT, bskip, bmsg, out);
}

// Round 2
// 395.390 us; speedup vs baseline: 3.3815x; 3.3815x over previous
//
#include <hip/hip_runtime.h>

#define N_NODES 100000
#define N_EDGES 640000
#define D 128
#define NB ((N_NODES + 1023) / 1024)   // 98 scan blocks

// ---------------------------------------------------------------------------
// k_init: zero deg_src[N], cnt_dst[N], cur[N] (contiguous 3*N ints)
// ---------------------------------------------------------------------------
__global__ __launch_bounds__(256) void k_init(int* __restrict__ z) {
    int i = blockIdx.x * blockDim.x + threadIdx.x;
    if (i < 3 * N_NODES) z[i] = 0;
}

// ---------------------------------------------------------------------------
// k_count: deg_src[src[e]]++ (for normalization), cnt_dst[dst[e]]++ (for CSR)
// ---------------------------------------------------------------------------
__global__ __launch_bounds__(256) void k_count(const int* __restrict__ src,
                                               const int* __restrict__ dst,
                                               int* __restrict__ deg_src,
                                               int* __restrict__ cnt_dst) {
    int e = blockIdx.x * blockDim.x + threadIdx.x;
    if (e < N_EDGES) {
        atomicAdd(&deg_src[src[e]], 1);
        atomicAdd(&cnt_dst[dst[e]], 1);
    }
}

// ---------------------------------------------------------------------------
// Exclusive scan of cnt_dst[N] -> rowptr[N], hierarchical (3 kernels).
// ---------------------------------------------------------------------------
__global__ __launch_bounds__(256) void k_scan1(const int* __restrict__ cnt,
                                               int* __restrict__ rowptr,
                                               int* __restrict__ bsums) {
    __shared__ int sd[256];
    int t = threadIdx.x;
    int i0 = blockIdx.x * 1024 + t * 4;
    int v[4];
    int s = 0;
#pragma unroll
    for (int q = 0; q < 4; q++) {
        int i = i0 + q;
        v[q] = (i < N_NODES) ? cnt[i] : 0;
        s += v[q];
    }
    sd[t] = s;
    __syncthreads();
    for (int off = 1; off < 256; off <<= 1) {
        int y = (t >= off) ? sd[t - off] : 0;
        __syncthreads();
        sd[t] += y;
        __syncthreads();
    }
    int run = sd[t] - s;   // exclusive prefix of this thread within block
    if (t == 255) bsums[blockIdx.x] = sd[255];
#pragma unroll
    for (int q = 0; q < 4; q++) {
        int i = i0 + q;
        if (i < N_NODES) rowptr[i] = run;
        run += v[q];
    }
}

__global__ __launch_bounds__(128) void k_scan2(int* __restrict__ bsums,
                                               int* __restrict__ rowptr) {
    __shared__ int sd[128];
    int t = threadIdx.x;
    int v = (t < NB) ? bsums[t] : 0;
    sd[t] = v;
    __syncthreads();
    for (int off = 1; off < 128; off <<= 1) {
        int y = (t >= off) ? sd[t - off] : 0;
        __syncthreads();
        sd[t] += y;
        __syncthreads();
    }
    if (t < NB) bsums[t] = sd[t] - v;   // exclusive
    if (t == 0) rowptr[N_NODES] = N_EDGES;
}

__global__ __launch_bounds__(256) void k_scan3(const int* __restrict__ bsums,
                                               int* __restrict__ rowptr) {
    int add = bsums[blockIdx.x];
    int i0 = blockIdx.x * 1024 + threadIdx.x * 4;
#pragma unroll
    for (int q = 0; q < 4; q++) {
        int i = i0 + q;
        if (i < N_NODES) rowptr[i] += add;
    }
}

// ---------------------------------------------------------------------------
// k_fill: csr_src[rowptr[dst[e]] + cur[dst[e]]++] = src[e]
// ---------------------------------------------------------------------------
__global__ __launch_bounds__(256) void k_fill(const int* __restrict__ src,
                                              const int* __restrict__ dst,
                                              const int* __restrict__ rowptr,
                                              int* __restrict__ cur,
                                              int* __restrict__ csr_src) {
    int e = blockIdx.x * blockDim.x + threadIdx.x;
    if (e < N_EDGES) {
        int d = dst[e];
        int p = atomicAdd(&cur[d], 1);
        csr_src[rowptr[d] + p] = src[e];
    }
}

// ---------------------------------------------------------------------------
// k_dis_w: dis[n] = deg>0 ? deg^-0.5 : 0 ; transpose both weight matrices.
// ---------------------------------------------------------------------------
__global__ __launch_bounds__(256) void k_dis_w(const int* __restrict__ deg,
                                               float* __restrict__ dis,
                                               const float* __restrict__ Wm,
                                               const float* __restrict__ Ws,
                                               float* __restrict__ WmT,
                                               float* __restrict__ WsT) {
    int i = blockIdx.x * blockDim.x + threadIdx.x;
    if (i < N_NODES) {
        int d = deg[i];
        dis[i] = (d > 0) ? (1.0f / sqrtf((float)d)) : 0.0f;
    }
    if (i < D * D) {
        int j = i >> 7;    // source row (output col)
        int k = i & 127;   // source col (k index)
        WmT[k * D + j] = Wm[i];
        WsT[k * D + j] = Ws[i];
    }
}

// ---------------------------------------------------------------------------
// k_agg: one wave per node: out[n] = sum_{e in CSR[n]} feats[src_e]*dis[src_e]
// Lanes preload up to 64 edge (src, dis) pairs, __shfl-broadcast each edge,
// gather feats as float2/lane (coalesced 512B), accumulate in registers,
// single write per row. No fp32 atomics.
// ---------------------------------------------------------------------------
__global__ __launch_bounds__(256) void k_agg(const float* __restrict__ feats,
                                             const int* __restrict__ rowptr,
                                             const int* __restrict__ csr_src,
                                             const float* __restrict__ dis,
                                             float* __restrict__ out) {
    int wid = (int)((blockIdx.x * (unsigned)blockDim.x + threadIdx.x) >> 6);
    int lane = threadIdx.x & 63;
    if (wid >= N_NODES) return;
    int start = rowptr[wid];
    int end = rowptr[wid + 1];
    float ax = 0.f, ay = 0.f;
    for (int base = start; base < end; base += 64) {
        int m = end - base;
        if (m > 64) m = 64;
        int s_l = 0;
        float sc_l = 0.f;
        if (lane < m) {
            s_l = csr_src[base + lane];
            sc_l = dis[s_l];
        }
        for (int i = 0; i < m; i++) {
            int s = __shfl(s_l, i);
            float sc = __shfl(sc_l, i);
            float2 v = ((const float2*)(feats + (size_t)s * D))[lane];
            ax += v.x * sc;
            ay += v.y * sc;
        }
    }
    float2 r;
    r.x = ax;
    r.y = ay;
    ((float2*)(out + (size_t)wid * D))[lane] = r;
}

// ---------------------------------------------------------------------------
// k_out: out[n] = (agg[n]*dis[n]) @ Wmsg^T + bmsg + feats[n] @ Wskip^T + bskip
// Block: 32 rows x 128 cols, 256 threads (64,4). Each thread: 2 cols x 8 rows.
// agg rows staged to LDS before being overwritten in place (row-local, safe).
// ---------------------------------------------------------------------------
#define TR 32
__global__ __launch_bounds__(256) void k_out(const float* __restrict__ feats,
                                             const float* __restrict__ dis,
                                             const float* __restrict__ WmT,
                                             const float* __restrict__ WsT,
                                             const float* __restrict__ bskip,
                                             const float* __restrict__ bmsg,
                                             float* __restrict__ out) {
    __shared__ float As[TR][D];
    __shared__ float Fs[TR][D];
    int tx = threadIdx.x;            // 0..63
    int ty = threadIdx.y;            // 0..3
    int tid = ty * 64 + tx;
    int row0 = blockIdx.x * TR;

    for (int i = tid; i < TR * (D / 4); i += 256) {
        int r  = i >> 5;
        int c4 = i & 31;
        int n = row0 + r;
        float4 a = make_float4(0.f, 0.f, 0.f, 0.f);
        float4 f = a;
        if (n < N_NODES) {
            float sc = dis[n];
            a = ((const float4*)(out + (size_t)n * D))[c4];
            a.x *= sc; a.y *= sc; a.z *= sc; a.w *= sc;
            f = ((const float4*)(feats + (size_t)n * D))[c4];
        }
        ((float4*)&As[r][0])[c4] = a;
        ((float4*)&Fs[r][0])[c4] = f;
    }
    __syncthreads();

    float acc0[8], acc1[8];
#pragma unroll
    for (int r = 0; r < 8; r++) { acc0[r] = 0.f; acc1[r] = 0.f; }

    for (int k = 0; k < D; k += 4) {
        float wm0[4], wm1[4], ws0[4], ws1[4];
#pragma unroll
        for (int q = 0; q < 4; q++) {
            wm0[q] = WmT[(k + q) * D + tx];
            wm1[q] = WmT[(k + q) * D + tx + 64];
            ws0[q] = WsT[(k + q) * D + tx];
            ws1[q] = WsT[(k + q) * D + tx + 64];
        }
#pragma unroll
        for (int r = 0; r < 8; r++) {
            int rr = ty + 4 * r;
            float4 a = *(const float4*)&As[rr][k];
            float4 f = *(const float4*)&Fs[rr][k];
            acc0[r] += a.x * wm0[0] + a.y * wm0[1] + a.z * wm0[2] + a.w * wm0[3]
                     + f.x * ws0[0] + f.y * ws0[1] + f.z * ws0[2] + f.w * ws0[3];
            acc1[r] += a.x * wm1[0] + a.y * wm1[1] + a.z * wm1[2] + a.w * wm1[3]
                     + f.x * ws1[0] + f.y * ws1[1] + f.z * ws1[2] + f.w * ws1[3];
        }
    }

    float b0 = bmsg[tx]      + bskip[tx];
    float b1 = bmsg[tx + 64] + bskip[tx + 64];
#pragma unroll
    for (int r = 0; r < 8; r++) {
        int n = row0 + ty + 4 * r;
        if (n < N_NODES) {
            out[(size_t)n * D + tx]      = acc0[r] + b0;
            out[(size_t)n * D + tx + 64] = acc1[r] + b1;
        }
    }
}

// ---------------------------------------------------------------------------
extern "C" void kernel_launch(void* const* d_in, const int* in_sizes, int n_in,
                              void* d_out, int out_size, void* d_ws, size_t ws_size,
                              hipStream_t stream) {
    const float* feats = (const float*)d_in[0];
    const int*   src   = (const int*)d_in[1];
    const int*   dst   = (const int*)d_in[2];
    const float* Wskip = (const float*)d_in[3];
    const float* bskip = (const float*)d_in[4];
    const float* Wmsg  = (const float*)d_in[5];
    const float* bmsg  = (const float*)d_in[6];
    float* out = (float*)d_out;

    // workspace layout:
    //   [0,       400000)   int   deg_src[N]
    //   [400000,  800000)   int   cnt_dst[N]
    //   [800000, 1200000)   int   cur[N]
    //   [1200000,1600000)   float dis[N]
    //   [1600000,2000128)   int   rowptr[N+1] (padded)
    //   [2000128,2000640)   int   bsums[128]
    //   [2000640,2066176)   float WmT[128*128]
    //   [2066176,2131712)   float WsT[128*128]
    //   [2131712,4691712)   int   csr_src[E]
    char* w = (char*)d_ws;
    int*   deg_src = (int*)w;
    int*   cnt_dst = (int*)(w + 400000);
    int*   cur     = (int*)(w + 800000);
    float* dis     = (float*)(w + 1200000);
    int*   rowptr  = (int*)(w + 1600000);
    int*   bsums   = (int*)(w + 2000128);
    float* WmT     = (float*)(w + 2000640);
    float* WsT     = (float*)(w + 2066176);
    int*   csr_src = (int*)(w + 2131712);

    hipLaunchKernelGGL(k_init, dim3((3 * N_NODES + 255) / 256), dim3(256), 0, stream,
                       deg_src);
    hipLaunchKernelGGL(k_count, dim3((N_EDGES + 255) / 256), dim3(256), 0, stream,
                       src, dst, deg_src, cnt_dst);
    hipLaunchKernelGGL(k_scan1, dim3(NB), dim3(256), 0, stream,
                       cnt_dst, rowptr, bsums);
    hipLaunchKernelGGL(k_scan2, dim3(1), dim3(128), 0, stream, bsums, rowptr);
    hipLaunchKernelGGL(k_scan3, dim3(NB), dim3(256), 0, stream, bsums, rowptr);
    hipLaunchKernelGGL(k_fill, dim3((N_EDGES + 255) / 256), dim3(256), 0, stream,
                       src, dst, rowptr, cur, csr_src);
    hipLaunchKernelGGL(k_dis_w, dim3((N_NODES + 255) / 256), dim3(256), 0, stream,
                       deg_src, dis, Wmsg, Wskip, WmT, WsT);
    hipLaunchKernelGGL(k_agg, dim3((N_NODES * 64 + 255) / 256), dim3(256), 0, stream,
                       feats, rowptr, csr_src, dis, out);
    hipLaunchKernelGGL(k_out, dim3((N_NODES + TR - 1) / TR), dim3(64, 4), 0, stream,
                       feats, dis, WmT, WsT, bskip, bmsg, out);
}

// Round 3
// 293.732 us; speedup vs baseline: 4.5517x; 1.3461x over previous
//
#include <hip/hip_runtime.h>

#define N_NODES 100000
#define N_EDGES 640000
#define D 128
#define NB ((N_NODES + 1023) / 1024)   // 98 scan blocks

typedef short v8s __attribute__((ext_vector_type(8)));
typedef float v4f __attribute__((ext_vector_type(4)));

__device__ __forceinline__ unsigned short f2bf(float x) {
    unsigned int u = __builtin_bit_cast(unsigned int, x);
    u += 0x7fffu + ((u >> 16) & 1u);   // RNE
    return (unsigned short)(u >> 16);
}
__device__ __forceinline__ float bf2f(unsigned int hi) {
    return __builtin_bit_cast(float, hi << 16);
}

// ---------------------------------------------------------------------------
// k_init: zero deg_src[N], cnt_dst[N], cur[N] (contiguous 3*N ints)
// ---------------------------------------------------------------------------
__global__ __launch_bounds__(256) void k_init(int* __restrict__ z) {
    int i = blockIdx.x * blockDim.x + threadIdx.x;
    if (i < 3 * N_NODES) z[i] = 0;
}

// ---------------------------------------------------------------------------
// k_count: deg_src[src[e]]++ , cnt_dst[dst[e]]++
// ---------------------------------------------------------------------------
__global__ __launch_bounds__(256) void k_count(const int* __restrict__ src,
                                               const int* __restrict__ dst,
                                               int* __restrict__ deg_src,
                                               int* __restrict__ cnt_dst) {
    int e = blockIdx.x * blockDim.x + threadIdx.x;
    if (e < N_EDGES) {
        atomicAdd(&deg_src[src[e]], 1);
        atomicAdd(&cnt_dst[dst[e]], 1);
    }
}

// ---------------------------------------------------------------------------
// Exclusive scan of cnt_dst[N] -> rowptr[N] (3 kernels)
// ---------------------------------------------------------------------------
__global__ __launch_bounds__(256) void k_scan1(const int* __restrict__ cnt,
                                               int* __restrict__ rowptr,
                                               int* __restrict__ bsums) {
    __shared__ int sd[256];
    int t = threadIdx.x;
    int i0 = blockIdx.x * 1024 + t * 4;
    int v[4];
    int s = 0;
#pragma unroll
    for (int q = 0; q < 4; q++) {
        int i = i0 + q;
        v[q] = (i < N_NODES) ? cnt[i] : 0;
        s += v[q];
    }
    sd[t] = s;
    __syncthreads();
    for (int off = 1; off < 256; off <<= 1) {
        int y = (t >= off) ? sd[t - off] : 0;
        __syncthreads();
        sd[t] += y;
        __syncthreads();
    }
    int run = sd[t] - s;
    if (t == 255) bsums[blockIdx.x] = sd[255];
#pragma unroll
    for (int q = 0; q < 4; q++) {
        int i = i0 + q;
        if (i < N_NODES) rowptr[i] = run;
        run += v[q];
    }
}

__global__ __launch_bounds__(128) void k_scan2(int* __restrict__ bsums,
                                               int* __restrict__ rowptr) {
    __shared__ int sd[128];
    int t = threadIdx.x;
    int v = (t < NB) ? bsums[t] : 0;
    sd[t] = v;
    __syncthreads();
    for (int off = 1; off < 128; off <<= 1) {
        int y = (t >= off) ? sd[t - off] : 0;
        __syncthreads();
        sd[t] += y;
        __syncthreads();
    }
    if (t < NB) bsums[t] = sd[t] - v;
    if (t == 0) rowptr[N_NODES] = N_EDGES;
}

__global__ __launch_bounds__(256) void k_scan3(const int* __restrict__ bsums,
                                               int* __restrict__ rowptr) {
    int add = bsums[blockIdx.x];
    int i0 = blockIdx.x * 1024 + threadIdx.x * 4;
#pragma unroll
    for (int q = 0; q < 4; q++) {
        int i = i0 + q;
        if (i < N_NODES) rowptr[i] += add;
    }
}

// ---------------------------------------------------------------------------
// k_fill: csr_src[rowptr[dst[e]] + cur[dst[e]]++] = src[e]
// ---------------------------------------------------------------------------
__global__ __launch_bounds__(256) void k_fill(const int* __restrict__ src,
                                              const int* __restrict__ dst,
                                              const int* __restrict__ rowptr,
                                              int* __restrict__ cur,
                                              int* __restrict__ csr_src) {
    int e = blockIdx.x * blockDim.x + threadIdx.x;
    if (e < N_EDGES) {
        int d = dst[e];
        int p = atomicAdd(&cur[d], 1);
        csr_src[rowptr[d] + p] = src[e];
    }
}

// ---------------------------------------------------------------------------
// k_dis: dis[n] = deg>0 ? deg^-0.5 : 0
// ---------------------------------------------------------------------------
__global__ __launch_bounds__(256) void k_dis(const int* __restrict__ deg,
                                             float* __restrict__ dis) {
    int i = blockIdx.x * blockDim.x + threadIdx.x;
    if (i < N_NODES) {
        int d = deg[i];
        dis[i] = (d > 0) ? (1.0f / sqrtf((float)d)) : 0.0f;
    }
}

// ---------------------------------------------------------------------------
// k_prep_w: Bcat[j][0:128]=bf16(Wm[j]), Bcat[j][128:256]=bf16(Ws[j]);
//           bias[j] = bmsg[j] + bskip[j]
// ---------------------------------------------------------------------------
__global__ __launch_bounds__(256) void k_prep_w(const float* __restrict__ Wm,
                                                const float* __restrict__ Ws,
                                                const float* __restrict__ bmsg,
                                                const float* __restrict__ bskip,
                                                unsigned short* __restrict__ Bcat,
                                                float* __restrict__ bias) {
    int i = blockIdx.x * blockDim.x + threadIdx.x;
    if (i < D * D) {
        int j = i >> 7;
        int k = i & 127;
        Bcat[j * 256 + k]       = f2bf(Wm[i]);
        Bcat[j * 256 + 128 + k] = f2bf(Ws[i]);
    }
    if (i < D) bias[i] = bmsg[i] + bskip[i];
}

// ---------------------------------------------------------------------------
// k_prep_f: featsh (bf16) packed into the SECOND 256B of each 512B d_out row.
// ---------------------------------------------------------------------------
__global__ __launch_bounds__(256) void k_prep_f(const float* __restrict__ feats,
                                                char* __restrict__ outb) {
    int i = blockIdx.x * blockDim.x + threadIdx.x;   // 1.6M threads, 8 elems each
    int g = i * 8;
    int row = g >> 7;
    int col = g & 127;
    if (row < N_NODES) {
        const float4* s = (const float4*)(feats + g);
        float4 x = s[0], y = s[1];
        uint4 p;
        p.x = (unsigned)f2bf(x.x) | ((unsigned)f2bf(x.y) << 16);
        p.y = (unsigned)f2bf(x.z) | ((unsigned)f2bf(x.w) << 16);
        p.z = (unsigned)f2bf(y.x) | ((unsigned)f2bf(y.y) << 16);
        p.w = (unsigned)f2bf(y.z) | ((unsigned)f2bf(y.w) << 16);
        *(uint4*)(outb + (size_t)row * 512 + 256 + col * 2) = p;
    }
}

// ---------------------------------------------------------------------------
// k_agg: wave per node. aggh[n] = dis[n] * sum_e featsh[src_e]*dis[src_e],
// written bf16 into the FIRST 256B of d_out row n. Gathers read featsh (bf16,
// 256B/edge). fp32 accumulation, no atomics.
// ---------------------------------------------------------------------------
__global__ __launch_bounds__(256) void k_agg(char* __restrict__ outb,
                                             const int* __restrict__ rowptr,
                                             const int* __restrict__ csr_src,
                                             const float* __restrict__ dis) {
    int wid = (int)((blockIdx.x * (unsigned)blockDim.x + threadIdx.x) >> 6);
    int lane = threadIdx.x & 63;
    if (wid >= N_NODES) return;
    int start = rowptr[wid];
    int end = rowptr[wid + 1];
    float ax = 0.f, ay = 0.f;
    for (int base = start; base < end; base += 64) {
        int m = end - base;
        if (m > 64) m = 64;
        int s_l = 0;
        float sc_l = 0.f;
        if (lane < m) {
            s_l = csr_src[base + lane];
            sc_l = dis[s_l];
        }
        for (int i = 0; i < m; i++) {
            int s = __shfl(s_l, i);
            float sc = __shfl(sc_l, i);
            unsigned int v = *(const unsigned int*)(outb + (size_t)s * 512 + 256 + lane * 4);
            ax += bf2f(v & 0xffffu) * sc;
            ay += bf2f(v >> 16) * sc;
        }
    }
    float scn = dis[wid];
    ax *= scn;
    ay *= scn;
    unsigned int p = (unsigned)f2bf(ax) | ((unsigned)f2bf(ay) << 16);
    *(unsigned int*)(outb + (size_t)wid * 512 + lane * 4) = p;
}

// ---------------------------------------------------------------------------
// k_gemm: out[n,:] = Arow[n] @ Bcat^T + bias, MFMA 16x16x32 bf16, K=256.
// Arow = the packed [aggh|featsh] bf16 rows living in d_out; overwritten in
// place with the fp32 result (block-local rows; store depends on all loads
// through the accumulator, so no hazard).
// Block: 128 rows, 4 waves; wave = 32 rows x 128 cols = 2x8 MFMA tiles.
// Bcat staged in LDS with +8-ushort row pad (even bank spread).
// ---------------------------------------------------------------------------
__global__ __launch_bounds__(256) void k_gemm(const unsigned short* __restrict__ Bcat,
                                              const float* __restrict__ bias,
                                              float* __restrict__ outf) {
    __shared__ unsigned short Bl[128][264];
    const char* Ab = (const char*)outf;
    int tid = threadIdx.x;
    int lane = tid & 63;
    int w = tid >> 6;
    int n0 = blockIdx.x * 128;

    // stage Bcat (128 x 256 bf16) -> LDS, coalesced 16B chunks
    for (int i = tid; i < 128 * 32; i += 256) {
        int r = i >> 5, c = i & 31;
        *(uint4*)(&Bl[r][c * 8]) = *(const uint4*)(Bcat + r * 256 + c * 8);
    }
    __syncthreads();

    int q = lane >> 4;     // quad 0..3 -> k-subchunk
    int lr = lane & 15;    // row/col within tile

    int r0 = n0 + w * 32 + lr;      if (r0 > N_NODES - 1) r0 = N_NODES - 1;
    int r1 = n0 + w * 32 + 16 + lr; if (r1 > N_NODES - 1) r1 = N_NODES - 1;
    const char* a0p = Ab + (size_t)r0 * 512 + q * 16;
    const char* a1p = Ab + (size_t)r1 * 512 + q * 16;

    v4f acc[2][8];
#pragma unroll
    for (int mt = 0; mt < 2; mt++)
#pragma unroll
        for (int t = 0; t < 8; t++) acc[mt][t] = (v4f){0.f, 0.f, 0.f, 0.f};

#pragma unroll
    for (int kk = 0; kk < 8; kk++) {           // K = 8 * 32
        v8s a0 = *(const v8s*)(a0p + kk * 64);
        v8s a1 = *(const v8s*)(a1p + kk * 64);
#pragma unroll
        for (int t = 0; t < 8; t++) {
            v8s b = *(const v8s*)(&Bl[t * 16 + lr][kk * 32 + q * 8]);
            acc[0][t] = __builtin_amdgcn_mfma_f32_16x16x32_bf16(a0, b, acc[0][t], 0, 0, 0);
            acc[1][t] = __builtin_amdgcn_mfma_f32_16x16x32_bf16(a1, b, acc[1][t], 0, 0, 0);
        }
    }

    // epilogue: C/D layout col=lane&15, row=(lane>>4)*4+reg
#pragma unroll
    for (int t = 0; t < 8; t++) {
        float bv = bias[t * 16 + lr];
#pragma unroll
        for (int mt = 0; mt < 2; mt++) {
            int rowb = n0 + w * 32 + mt * 16 + q * 4;
#pragma unroll
            for (int r = 0; r < 4; r++) {
                int row = rowb + r;
                if (row < N_NODES)
                    outf[(size_t)row * 128 + t * 16 + lr] = acc[mt][t][r] + bv;
            }
        }
    }
}

// ---------------------------------------------------------------------------
extern "C" void kernel_launch(void* const* d_in, const int* in_sizes, int n_in,
                              void* d_out, int out_size, void* d_ws, size_t ws_size,
                              hipStream_t stream) {
    const float* feats = (const float*)d_in[0];
    const int*   src   = (const int*)d_in[1];
    const int*   dst   = (const int*)d_in[2];
    const float* Wskip = (const float*)d_in[3];
    const float* bskip = (const float*)d_in[4];
    const float* Wmsg  = (const float*)d_in[5];
    const float* bmsg  = (const float*)d_in[6];

    // workspace layout:
    //   [0,       400000)   int   deg_src[N]
    //   [400000,  800000)   int   cnt_dst[N]
    //   [800000, 1200000)   int   cur[N]
    //   [1200000,1600000)   float dis[N]
    //   [1600000,2000128)   int   rowptr[N+1] (padded)
    //   [2000128,2000640)   int   bsums[128]
    //   [2000640,2066176)   ushort Bcat[128*256]
    //   [2066176,2066688)   float bias[128]
    //   [2066688,4626688)   int   csr_src[E]
    char* w = (char*)d_ws;
    int*            deg_src = (int*)w;
    int*            cnt_dst = (int*)(w + 400000);
    int*            cur     = (int*)(w + 800000);
    float*          dis     = (float*)(w + 1200000);
    int*            rowptr  = (int*)(w + 1600000);
    int*            bsums   = (int*)(w + 2000128);
    unsigned short* Bcat    = (unsigned short*)(w + 2000640);
    float*          bias    = (float*)(w + 2066176);
    int*            csr_src = (int*)(w + 2066688);

    hipLaunchKernelGGL(k_init, dim3((3 * N_NODES + 255) / 256), dim3(256), 0, stream,
                       deg_src);
    hipLaunchKernelGGL(k_count, dim3((N_EDGES + 255) / 256), dim3(256), 0, stream,
                       src, dst, deg_src, cnt_dst);
    hipLaunchKernelGGL(k_scan1, dim3(NB), dim3(256), 0, stream,
                       cnt_dst, rowptr, bsums);
    hipLaunchKernelGGL(k_scan2, dim3(1), dim3(128), 0, stream, bsums, rowptr);
    hipLaunchKernelGGL(k_scan3, dim3(NB), dim3(256), 0, stream, bsums, rowptr);
    hipLaunchKernelGGL(k_fill, dim3((N_EDGES + 255) / 256), dim3(256), 0, stream,
                       src, dst, rowptr, cur, csr_src);
    hipLaunchKernelGGL(k_dis, dim3((N_NODES + 255) / 256), dim3(256), 0, stream,
                       deg_src, dis);
    hipLaunchKernelGGL(k_prep_w, dim3((D * D + 255) / 256), dim3(256), 0, stream,
                       Wmsg, Wskip, bmsg, bskip, Bcat, bias);
    hipLaunchKernelGGL(k_prep_f, dim3((N_NODES * (D / 8) + 255) / 256), dim3(256), 0,
                       stream, feats, (char*)d_out);
    hipLaunchKernelGGL(k_agg, dim3((N_NODES * 64 + 255) / 256), dim3(256), 0, stream,
                       (char*)d_out, rowptr, csr_src, dis);
    hipLaunchKernelGGL(k_gemm, dim3((N_NODES + 127) / 128), dim3(256), 0, stream,
                       Bcat, bias, (float*)d_out);
}

// Round 4
// 274.468 us; speedup vs baseline: 4.8712x; 1.0702x over previous
//
#include <hip/hip_runtime.h>

#define N_NODES 100000
#define N_EDGES 640000
#define D 128
#define NB ((N_NODES + 1023) / 1024)   // 98 scan blocks

typedef short v8s __attribute__((ext_vector_type(8)));
typedef float v4f __attribute__((ext_vector_type(4)));

__device__ __forceinline__ unsigned short f2bf(float x) {
    unsigned int u = __builtin_bit_cast(unsigned int, x);
    u += 0x7fffu + ((u >> 16) & 1u);   // RNE
    return (unsigned short)(u >> 16);
}
__device__ __forceinline__ float bf2f(unsigned int hi) {
    return __builtin_bit_cast(float, hi << 16);
}

// ---------------------------------------------------------------------------
// k_pre (fused k_init + k_prep_w + k_prep_f):
//   - zero deg_src/cnt_dst/cur (3*N ints, contiguous)
//   - Bcat[j][0:128]=bf16(Wm[j]), Bcat[j][128:256]=bf16(Ws[j]); bias=bm+bs
//   - featsh (bf16) packed into the SECOND 256B of each 512B d_out row
// Grid sized for the featsh pack: N*(D/8) = 1.6M threads.
// ---------------------------------------------------------------------------
__global__ __launch_bounds__(256) void k_pre(const float* __restrict__ feats,
                                             const float* __restrict__ Wm,
                                             const float* __restrict__ Ws,
                                             const float* __restrict__ bmsg,
                                             const float* __restrict__ bskip,
                                             int* __restrict__ z,
                                             unsigned short* __restrict__ Bcat,
                                             float* __restrict__ bias,
                                             char* __restrict__ outb) {
    int i = blockIdx.x * blockDim.x + threadIdx.x;
    if (i < 3 * N_NODES) z[i] = 0;
    if (i < D * D) {
        int j = i >> 7;
        int k = i & 127;
        Bcat[j * 256 + k]       = f2bf(Wm[i]);
        Bcat[j * 256 + 128 + k] = f2bf(Ws[i]);
    }
    if (i < D) bias[i] = bmsg[i] + bskip[i];
    int g = i * 8;
    int row = g >> 7;
    int col = g & 127;
    if (row < N_NODES) {
        const float4* s = (const float4*)(feats + g);
        float4 x = s[0], y = s[1];
        uint4 p;
        p.x = (unsigned)f2bf(x.x) | ((unsigned)f2bf(x.y) << 16);
        p.y = (unsigned)f2bf(x.z) | ((unsigned)f2bf(x.w) << 16);
        p.z = (unsigned)f2bf(y.x) | ((unsigned)f2bf(y.y) << 16);
        p.w = (unsigned)f2bf(y.z) | ((unsigned)f2bf(y.w) << 16);
        *(uint4*)(outb + (size_t)row * 512 + 256 + col * 2) = p;
    }
}

// ---------------------------------------------------------------------------
// k_count: deg_src[src[e]]++ , cnt_dst[dst[e]]++
// ---------------------------------------------------------------------------
__global__ __launch_bounds__(256) void k_count(const int* __restrict__ src,
                                               const int* __restrict__ dst,
                                               int* __restrict__ deg_src,
                                               int* __restrict__ cnt_dst) {
    int e = blockIdx.x * blockDim.x + threadIdx.x;
    if (e < N_EDGES) {
        atomicAdd(&deg_src[src[e]], 1);
        atomicAdd(&cnt_dst[dst[e]], 1);
    }
}

// ---------------------------------------------------------------------------
// Exclusive scan of cnt_dst[N] -> rowptr[N] (3 kernels)
// ---------------------------------------------------------------------------
__global__ __launch_bounds__(256) void k_scan1(const int* __restrict__ cnt,
                                               int* __restrict__ rowptr,
                                               int* __restrict__ bsums) {
    __shared__ int sd[256];
    int t = threadIdx.x;
    int i0 = blockIdx.x * 1024 + t * 4;
    int v[4];
    int s = 0;
#pragma unroll
    for (int q = 0; q < 4; q++) {
        int i = i0 + q;
        v[q] = (i < N_NODES) ? cnt[i] : 0;
        s += v[q];
    }
    sd[t] = s;
    __syncthreads();
    for (int off = 1; off < 256; off <<= 1) {
        int y = (t >= off) ? sd[t - off] : 0;
        __syncthreads();
        sd[t] += y;
        __syncthreads();
    }
    int run = sd[t] - s;
    if (t == 255) bsums[blockIdx.x] = sd[255];
#pragma unroll
    for (int q = 0; q < 4; q++) {
        int i = i0 + q;
        if (i < N_NODES) rowptr[i] = run;
        run += v[q];
    }
}

__global__ __launch_bounds__(128) void k_scan2(int* __restrict__ bsums,
                                               int* __restrict__ rowptr) {
    __shared__ int sd[128];
    int t = threadIdx.x;
    int v = (t < NB) ? bsums[t] : 0;
    sd[t] = v;
    __syncthreads();
    for (int off = 1; off < 128; off <<= 1) {
        int y = (t >= off) ? sd[t - off] : 0;
        __syncthreads();
        sd[t] += y;
        __syncthreads();
    }
    if (t < NB) bsums[t] = sd[t] - v;
    if (t == 0) rowptr[N_NODES] = N_EDGES;
}

// k_scan3 also computes dis[n] = deg>0 ? deg^-0.5 : 0 (fused, post-k_count)
__global__ __launch_bounds__(256) void k_scan3(const int* __restrict__ bsums,
                                               int* __restrict__ rowptr,
                                               const int* __restrict__ deg,
                                               float* __restrict__ dis) {
    int add = bsums[blockIdx.x];
    int i0 = blockIdx.x * 1024 + threadIdx.x * 4;
#pragma unroll
    for (int q = 0; q < 4; q++) {
        int i = i0 + q;
        if (i < N_NODES) {
            rowptr[i] += add;
            int d = deg[i];
            dis[i] = (d > 0) ? (1.0f / sqrtf((float)d)) : 0.0f;
        }
    }
}

// ---------------------------------------------------------------------------
// k_fill: csr_src[rowptr[dst[e]] + cur[dst[e]]++] = src[e]
// ---------------------------------------------------------------------------
__global__ __launch_bounds__(256) void k_fill(const int* __restrict__ src,
                                              const int* __restrict__ dst,
                                              const int* __restrict__ rowptr,
                                              int* __restrict__ cur,
                                              int* __restrict__ csr_src) {
    int e = blockIdx.x * blockDim.x + threadIdx.x;
    if (e < N_EDGES) {
        int d = dst[e];
        int p = atomicAdd(&cur[d], 1);
        csr_src[rowptr[d] + p] = src[e];
    }
}

// ---------------------------------------------------------------------------
// k_agg: one wave per node, 4 edges per iteration.
// Lane group g=lane>>4 handles edge base+g; its 16 lanes each load 16B
// (dwordx4) of the 256B bf16 featsh row. csr_src/dis reads are group-uniform
// (broadcast). No inner shfl. Butterfly (xor16,32) combines the 4 partial
// sums; group 0 writes aggh = dis[n]*sum (bf16) into the FIRST 256B of the
// d_out row.
// ---------------------------------------------------------------------------
__global__ __launch_bounds__(256) void k_agg(char* __restrict__ outb,
                                             const int* __restrict__ rowptr,
                                             const int* __restrict__ csr_src,
                                             const float* __restrict__ dis) {
    int wid = (int)((blockIdx.x * (unsigned)blockDim.x + threadIdx.x) >> 6);
    int lane = threadIdx.x & 63;
    if (wid >= N_NODES) return;
    int grp = lane >> 4;    // which edge within the 4-edge chunk
    int sub = lane & 15;    // 16B sub-chunk within the 256B row
    int start = rowptr[wid];
    int end = rowptr[wid + 1];
    float acc[8];
#pragma unroll
    for (int i = 0; i < 8; i++) acc[i] = 0.f;

    for (int base = start; base < end; base += 4) {
        int e = base + grp;
        if (e < end) {
            int s = csr_src[e];
            float sc = dis[s];
            uint4 v = *(const uint4*)(outb + (size_t)s * 512 + 256 + sub * 16);
            acc[0] += bf2f(v.x & 0xffffu) * sc;
            acc[1] += bf2f(v.x >> 16) * sc;
            acc[2] += bf2f(v.y & 0xffffu) * sc;
            acc[3] += bf2f(v.y >> 16) * sc;
            acc[4] += bf2f(v.z & 0xffffu) * sc;
            acc[5] += bf2f(v.z >> 16) * sc;
            acc[6] += bf2f(v.w & 0xffffu) * sc;
            acc[7] += bf2f(v.w >> 16) * sc;
        }
    }
#pragma unroll
    for (int i = 0; i < 8; i++) {
        acc[i] += __shfl_xor(acc[i], 16);
        acc[i] += __shfl_xor(acc[i], 32);
    }
    if (grp == 0) {
        float scn = dis[wid];
        uint4 p;
        p.x = (unsigned)f2bf(acc[0] * scn) | ((unsigned)f2bf(acc[1] * scn) << 16);
        p.y = (unsigned)f2bf(acc[2] * scn) | ((unsigned)f2bf(acc[3] * scn) << 16);
        p.z = (unsigned)f2bf(acc[4] * scn) | ((unsigned)f2bf(acc[5] * scn) << 16);
        p.w = (unsigned)f2bf(acc[6] * scn) | ((unsigned)f2bf(acc[7] * scn) << 16);
        *(uint4*)(outb + (size_t)wid * 512 + sub * 16) = p;
    }
}

// ---------------------------------------------------------------------------
// k_gemm: out[n,:] = Arow[n] @ Bcat^T + bias, MFMA 16x16x32 bf16, K=256.
// Arow = packed [aggh|featsh] bf16 rows in d_out; overwritten in place with
// the fp32 result (block-local rows; stores depend on all loads through the
// accumulator). Block: 128 rows, 4 waves; wave = 32 rows x 128 cols.
// ---------------------------------------------------------------------------
__global__ __launch_bounds__(256) void k_gemm(const unsigned short* __restrict__ Bcat,
                                              const float* __restrict__ bias,
                                              float* __restrict__ outf) {
    __shared__ unsigned short Bl[128][264];
    const char* Ab = (const char*)outf;
    int tid = threadIdx.x;
    int lane = tid & 63;
    int w = tid >> 6;
    int n0 = blockIdx.x * 128;

    for (int i = tid; i < 128 * 32; i += 256) {
        int r = i >> 5, c = i & 31;
        *(uint4*)(&Bl[r][c * 8]) = *(const uint4*)(Bcat + r * 256 + c * 8);
    }
    __syncthreads();

    int q = lane >> 4;
    int lr = lane & 15;

    int r0 = n0 + w * 32 + lr;      if (r0 > N_NODES - 1) r0 = N_NODES - 1;
    int r1 = n0 + w * 32 + 16 + lr; if (r1 > N_NODES - 1) r1 = N_NODES - 1;
    const char* a0p = Ab + (size_t)r0 * 512 + q * 16;
    const char* a1p = Ab + (size_t)r1 * 512 + q * 16;

    v4f acc[2][8];
#pragma unroll
    for (int mt = 0; mt < 2; mt++)
#pragma unroll
        for (int t = 0; t < 8; t++) acc[mt][t] = (v4f){0.f, 0.f, 0.f, 0.f};

#pragma unroll
    for (int kk = 0; kk < 8; kk++) {
        v8s a0 = *(const v8s*)(a0p + kk * 64);
        v8s a1 = *(const v8s*)(a1p + kk * 64);
#pragma unroll
        for (int t = 0; t < 8; t++) {
            v8s b = *(const v8s*)(&Bl[t * 16 + lr][kk * 32 + q * 8]);
            acc[0][t] = __builtin_amdgcn_mfma_f32_16x16x32_bf16(a0, b, acc[0][t], 0, 0, 0);
            acc[1][t] = __builtin_amdgcn_mfma_f32_16x16x32_bf16(a1, b, acc[1][t], 0, 0, 0);
        }
    }

#pragma unroll
    for (int t = 0; t < 8; t++) {
        float bv = bias[t * 16 + lr];
#pragma unroll
        for (int mt = 0; mt < 2; mt++) {
            int rowb = n0 + w * 32 + mt * 16 + q * 4;
#pragma unroll
            for (int r = 0; r < 4; r++) {
                int row = rowb + r;
                if (row < N_NODES)
                    outf[(size_t)row * 128 + t * 16 + lr] = acc[mt][t][r] + bv;
            }
        }
    }
}

// ---------------------------------------------------------------------------
extern "C" void kernel_launch(void* const* d_in, const int* in_sizes, int n_in,
                              void* d_out, int out_size, void* d_ws, size_t ws_size,
                              hipStream_t stream) {
    const float* feats = (const float*)d_in[0];
    const int*   src   = (const int*)d_in[1];
    const int*   dst   = (const int*)d_in[2];
    const float* Wskip = (const float*)d_in[3];
    const float* bskip = (const float*)d_in[4];
    const float* Wmsg  = (const float*)d_in[5];
    const float* bmsg  = (const float*)d_in[6];

    // workspace layout:
    //   [0,       400000)   int   deg_src[N]
    //   [400000,  800000)   int   cnt_dst[N]
    //   [800000, 1200000)   int   cur[N]
    //   [1200000,1600000)   float dis[N]
    //   [1600000,2000128)   int   rowptr[N+1] (padded)
    //   [2000128,2000640)   int   bsums[128]
    //   [2000640,2066176)   ushort Bcat[128*256]
    //   [2066176,2066688)   float bias[128]
    //   [2066688,4626688)   int   csr_src[E]
    char* w = (char*)d_ws;
    int*            deg_src = (int*)w;
    int*            cnt_dst = (int*)(w + 400000);
    int*            cur     = (int*)(w + 800000);
    float*          dis     = (float*)(w + 1200000);
    int*            rowptr  = (int*)(w + 1600000);
    int*            bsums   = (int*)(w + 2000128);
    unsigned short* Bcat    = (unsigned short*)(w + 2000640);
    float*          bias    = (float*)(w + 2066176);
    int*            csr_src = (int*)(w + 2066688);

    hipLaunchKernelGGL(k_pre, dim3((N_NODES * (D / 8) + 255) / 256), dim3(256), 0,
                       stream, feats, Wmsg, Wskip, bmsg, bskip, deg_src, Bcat, bias,
                       (char*)d_out);
    hipLaunchKernelGGL(k_count, dim3((N_EDGES + 255) / 256), dim3(256), 0, stream,
                       src, dst, deg_src, cnt_dst);
    hipLaunchKernelGGL(k_scan1, dim3(NB), dim3(256), 0, stream,
                       cnt_dst, rowptr, bsums);
    hipLaunchKernelGGL(k_scan2, dim3(1), dim3(128), 0, stream, bsums, rowptr);
    hipLaunchKernelGGL(k_scan3, dim3(NB), dim3(256), 0, stream, bsums, rowptr,
                       deg_src, dis);
    hipLaunchKernelGGL(k_fill, dim3((N_EDGES + 255) / 256), dim3(256), 0, stream,
                       src, dst, rowptr, cur, csr_src);
    hipLaunchKernelGGL(k_agg, dim3((N_NODES * 64 + 255) / 256), dim3(256), 0, stream,
                       (char*)d_out, rowptr, csr_src, dis);
    hipLaunchKernelGGL(k_gemm, dim3((N_NODES + 127) / 128), dim3(256), 0, stream,
                       Bcat, bias, (float*)d_out);
}